// Round 1
// baseline (1694.058 us; speedup 1.0000x reference)
//
#include <hip/hip_runtime.h>

#define CH 32
#define KOFF 27
#define BN_EPS 1e-5f

typedef short bf16x8 __attribute__((ext_vector_type(8)));
typedef float f32x4 __attribute__((ext_vector_type(4)));

__device__ __forceinline__ short f2bf(float f) {
    unsigned u = __builtin_bit_cast(unsigned, f);
    u = (u + 0x7fffu + ((u >> 16) & 1u)) >> 16;   // round-to-nearest-even
    return (short)u;
}

// One wave handles 16 rulebook pairs: gather 16 rows of x (each lane: 32B),
// 2x mfma_f32_16x16x32_bf16 against W[k], scatter-add D rows to y.
__global__ __launch_bounds__(256) void conv_kernel(
    const float* __restrict__ x, const float* __restrict__ W,
    const int* __restrict__ in_idx, const int* __restrict__ out_idx,
    float* __restrict__ y, int P, int tilesPerK, int tilesPerWave)
{
    const int k    = blockIdx.y;
    const int lane = threadIdx.x & 63;
    const int wv   = threadIdx.x >> 6;
    const int r16  = lane & 15;   // A row / D col
    const int g    = lane >> 4;   // 0..3

    // B fragments for W[k] (kept in regs for all tiles this wave processes).
    // B[kk][n]: lane holds kk = 8*g + j, n = r16 (+16 for second half).
    const float* Wk = W + k * CH * CH;
    bf16x8 b0, b1;
#pragma unroll
    for (int j = 0; j < 8; ++j) {
        int kk = g * 8 + j;
        b0[j] = f2bf(Wk[kk * CH + r16]);
        b1[j] = f2bf(Wk[kk * CH + 16 + r16]);
    }

    const int kP = k * P;
    int t0 = (blockIdx.x * 4 + wv) * tilesPerWave;
    int t1 = t0 + tilesPerWave;
    if (t1 > tilesPerK) t1 = tilesPerK;

    for (int t = t0; t < t1; ++t) {
        const int base = t * 16;
        // A fragment: row = r16 (pair), k-elems 8g..8g+7 -> contiguous 32B of x row
        int pi = base + r16;
        if (pi >= P) pi = P - 1;                 // clamp (scatter is guarded)
        const int ii = in_idx[kP + pi];
        const float* xr = x + ii * CH + g * 8;
        f32x4 x0 = *(const f32x4*)xr;
        f32x4 x1 = *(const f32x4*)(xr + 4);
        bf16x8 a;
        a[0] = f2bf(x0[0]); a[1] = f2bf(x0[1]); a[2] = f2bf(x0[2]); a[3] = f2bf(x0[3]);
        a[4] = f2bf(x1[0]); a[5] = f2bf(x1[1]); a[6] = f2bf(x1[2]); a[7] = f2bf(x1[3]);

        f32x4 d0 = {0.f, 0.f, 0.f, 0.f};
        f32x4 d1 = {0.f, 0.f, 0.f, 0.f};
        d0 = __builtin_amdgcn_mfma_f32_16x16x32_bf16(a, b0, d0, 0, 0, 0);
        d1 = __builtin_amdgcn_mfma_f32_16x16x32_bf16(a, b1, d1, 0, 0, 0);

        // D[row=(g*4+i)][col=r16 (+16)] -> scatter-add
#pragma unroll
        for (int i = 0; i < 4; ++i) {
            int pr = base + g * 4 + i;
            if (pr < P) {
                int oi = out_idx[kP + pr];
                atomicAdd(&y[oi * CH + r16], d0[i]);
                atomicAdd(&y[oi * CH + 16 + r16], d1[i]);
            }
        }
    }
}

__global__ __launch_bounds__(256) void stats_kernel(
    const f32x4* __restrict__ y4, float* __restrict__ stats, int n4)
{
    __shared__ float ls[CH], ls2[CH];
    if (threadIdx.x < CH) { ls[threadIdx.x] = 0.f; ls2[threadIdx.x] = 0.f; }
    __syncthreads();

    int tid = blockIdx.x * blockDim.x + threadIdx.x;
    int stride = gridDim.x * blockDim.x;      // *4 elems: multiple of 32 -> fixed channels
    float s0 = 0, s1 = 0, s2 = 0, s3 = 0;
    float q0 = 0, q1 = 0, q2 = 0, q3 = 0;
    for (int i = tid; i < n4; i += stride) {
        f32x4 v = y4[i];
        s0 += v[0]; q0 += v[0] * v[0];
        s1 += v[1]; q1 += v[1] * v[1];
        s2 += v[2]; q2 += v[2] * v[2];
        s3 += v[3]; q3 += v[3] * v[3];
    }
    int c = (tid * 4) & (CH - 1);
    atomicAdd(&ls[c + 0], s0); atomicAdd(&ls[c + 1], s1);
    atomicAdd(&ls[c + 2], s2); atomicAdd(&ls[c + 3], s3);
    atomicAdd(&ls2[c + 0], q0); atomicAdd(&ls2[c + 1], q1);
    atomicAdd(&ls2[c + 2], q2); atomicAdd(&ls2[c + 3], q3);
    __syncthreads();
    if (threadIdx.x < CH) {
        atomicAdd(&stats[threadIdx.x], ls[threadIdx.x]);
        atomicAdd(&stats[CH + threadIdx.x], ls2[threadIdx.x]);
    }
}

__global__ __launch_bounds__(256) void bn_relu_kernel(
    f32x4* __restrict__ y4, const float* __restrict__ stats,
    const float* __restrict__ gamma, const float* __restrict__ beta,
    float invN, int n4)
{
    __shared__ float sc[CH], bi[CH];
    if (threadIdx.x < CH) {
        int c = threadIdx.x;
        float mean = stats[c] * invN;
        float var  = stats[CH + c] * invN - mean * mean;   // biased, matches jnp.var
        float s = gamma[c] * rsqrtf(var + BN_EPS);
        sc[c] = s;
        bi[c] = beta[c] - mean * s;
    }
    __syncthreads();

    int tid = blockIdx.x * blockDim.x + threadIdx.x;
    int stride = gridDim.x * blockDim.x;
    for (int i = tid; i < n4; i += stride) {
        f32x4 v = y4[i];
        int c = (i * 4) & (CH - 1);
        f32x4 o;
        o[0] = fmaxf(v[0] * sc[c + 0] + bi[c + 0], 0.f);
        o[1] = fmaxf(v[1] * sc[c + 1] + bi[c + 1], 0.f);
        o[2] = fmaxf(v[2] * sc[c + 2] + bi[c + 2], 0.f);
        o[3] = fmaxf(v[3] * sc[c + 3] + bi[c + 3], 0.f);
        y4[i] = o;
    }
}

extern "C" void kernel_launch(void* const* d_in, const int* in_sizes, int n_in,
                              void* d_out, int out_size, void* d_ws, size_t ws_size,
                              hipStream_t stream)
{
    const float* x      = (const float*)d_in[0];
    const float* W      = (const float*)d_in[1];
    const float* gamma  = (const float*)d_in[2];
    const float* beta   = (const float*)d_in[3];
    const int*   in_idx = (const int*)d_in[4];
    const int*   out_idx= (const int*)d_in[5];
    float* y     = (float*)d_out;
    float* stats = (float*)d_ws;

    const int P = in_sizes[4] / KOFF;
    const int N = in_sizes[0] / CH;

    // y accumulator = d_out; zero it + the stats scratch every call.
    hipMemsetAsync(d_out, 0, (size_t)out_size * sizeof(float), stream);
    hipMemsetAsync(d_ws, 0, 2 * CH * sizeof(float), stream);

    const int tilesPerK = (P + 15) / 16;
    const int tilesPerWave = 8;
    const int blocksX = (tilesPerK + 4 * tilesPerWave - 1) / (4 * tilesPerWave);
    conv_kernel<<<dim3(blocksX, KOFF), 256, 0, stream>>>(
        x, W, in_idx, out_idx, y, P, tilesPerK, tilesPerWave);

    const int n4 = out_size / 4;
    stats_kernel<<<1024, 256, 0, stream>>>((const f32x4*)d_out, stats, n4);
    bn_relu_kernel<<<2048, 256, 0, stream>>>((f32x4*)d_out, stats, gamma, beta,
                                             1.0f / (float)N, n4);
}

// Round 2
// 900.097 us; speedup vs baseline: 1.8821x; 1.8821x over previous
//
#include <hip/hip_runtime.h>

#define CH 32
#define KOFF 27
#define BN_EPS 1e-5f

typedef short bf16x8 __attribute__((ext_vector_type(8)));
typedef float f32x4 __attribute__((ext_vector_type(4)));

__device__ __forceinline__ unsigned short f2bf(float f) {
    unsigned u = __builtin_bit_cast(unsigned, f);
    u = (u + 0x7fffu + ((u >> 16) & 1u)) >> 16;   // round-to-nearest-even
    return (unsigned short)u;
}
__device__ __forceinline__ float bf2f_lo(unsigned u) {
    return __builtin_bit_cast(float, u << 16);
}
__device__ __forceinline__ float bf2f_hi(unsigned u) {
    return __builtin_bit_cast(float, u & 0xffff0000u);
}

// ---------------- pk-bf16 accumulation path ----------------
// One wave = 16 rulebook pairs. B fragments column-permuted so lane's two
// output channels are adjacent (2*r16, 2*r16+1) -> one pk_add_bf16 per row.
__global__ __launch_bounds__(256) void conv_pk_kernel(
    const float* __restrict__ x, const float* __restrict__ W,
    const int* __restrict__ in_idx, const int* __restrict__ out_idx,
    unsigned* __restrict__ ybf,   // [N][16] uints, each = 2 bf16 channels
    int P, int tilesPerK, int tilesPerWave)
{
    const int k    = blockIdx.y;
    const int lane = threadIdx.x & 63;
    const int wv   = threadIdx.x >> 6;
    const int r16  = lane & 15;
    const int g    = lane >> 4;

    const float* Wk = W + k * CH * CH;
    bf16x8 b0, b1;   // b0: even channels, b1: odd channels
#pragma unroll
    for (int j = 0; j < 8; ++j) {
        int kk = g * 8 + j;
        b0[j] = (short)f2bf(Wk[kk * CH + 2 * r16]);
        b1[j] = (short)f2bf(Wk[kk * CH + 2 * r16 + 1]);
    }

    const int kP = k * P;
    int t0 = (blockIdx.x * 4 + wv) * tilesPerWave;
    int t1 = t0 + tilesPerWave;
    if (t1 > tilesPerK) t1 = tilesPerK;

    for (int t = t0; t < t1; ++t) {
        const int base = t * 16;
        int pi = base + r16;
        if (pi >= P) pi = P - 1;
        const int ii = in_idx[kP + pi];
        const float* xr = x + ii * CH + g * 8;
        f32x4 x0 = *(const f32x4*)xr;
        f32x4 x1 = *(const f32x4*)(xr + 4);
        bf16x8 a;
        a[0] = (short)f2bf(x0[0]); a[1] = (short)f2bf(x0[1]);
        a[2] = (short)f2bf(x0[2]); a[3] = (short)f2bf(x0[3]);
        a[4] = (short)f2bf(x1[0]); a[5] = (short)f2bf(x1[1]);
        a[6] = (short)f2bf(x1[2]); a[7] = (short)f2bf(x1[3]);

        f32x4 d0 = {0.f, 0.f, 0.f, 0.f};
        f32x4 d1 = {0.f, 0.f, 0.f, 0.f};
        d0 = __builtin_amdgcn_mfma_f32_16x16x32_bf16(a, b0, d0, 0, 0, 0);
        d1 = __builtin_amdgcn_mfma_f32_16x16x32_bf16(a, b1, d1, 0, 0, 0);

#pragma unroll
        for (int i = 0; i < 4; ++i) {
            int pr = base + g * 4 + i;
            if (pr < P) {
                int oi = out_idx[kP + pr];
                unsigned pk = (unsigned)f2bf(d0[i]) | ((unsigned)f2bf(d1[i]) << 16);
                unsigned* addr = ybf + (size_t)oi * (CH / 2) + r16;
                asm volatile("global_atomic_pk_add_bf16 %0, %1, off"
                             :: "v"(addr), "v"(pk) : "memory");
            }
        }
    }
}

__global__ __launch_bounds__(256) void stats_pk_kernel(
    const uint4* __restrict__ y4, float* __restrict__ stats, int n4)
{
    __shared__ float ls[CH], ls2[CH];
    if (threadIdx.x < CH) { ls[threadIdx.x] = 0.f; ls2[threadIdx.x] = 0.f; }
    __syncthreads();

    int tid = blockIdx.x * blockDim.x + threadIdx.x;
    int stride = gridDim.x * blockDim.x;
    float s[8] = {0,0,0,0,0,0,0,0}, q[8] = {0,0,0,0,0,0,0,0};
    for (int i = tid; i < n4; i += stride) {
        uint4 v = y4[i];
        float f0 = bf2f_lo(v.x), f1 = bf2f_hi(v.x);
        float f2 = bf2f_lo(v.y), f3 = bf2f_hi(v.y);
        float f4 = bf2f_lo(v.z), f5 = bf2f_hi(v.z);
        float f6 = bf2f_lo(v.w), f7 = bf2f_hi(v.w);
        s[0]+=f0; q[0]+=f0*f0; s[1]+=f1; q[1]+=f1*f1;
        s[2]+=f2; q[2]+=f2*f2; s[3]+=f3; q[3]+=f3*f3;
        s[4]+=f4; q[4]+=f4*f4; s[5]+=f5; q[5]+=f5*f5;
        s[6]+=f6; q[6]+=f6*f6; s[7]+=f7; q[7]+=f7*f7;
    }
    int c = (tid * 8) & (CH - 1);
#pragma unroll
    for (int j = 0; j < 8; ++j) {
        atomicAdd(&ls[c + j], s[j]);
        atomicAdd(&ls2[c + j], q[j]);
    }
    __syncthreads();
    if (threadIdx.x < CH) {
        atomicAdd(&stats[threadIdx.x], ls[threadIdx.x]);
        atomicAdd(&stats[CH + threadIdx.x], ls2[threadIdx.x]);
    }
}

__global__ __launch_bounds__(256) void bn_relu_pk_kernel(
    const uint4* __restrict__ y4, f32x4* __restrict__ out4,
    const float* __restrict__ stats,
    const float* __restrict__ gamma, const float* __restrict__ beta,
    float invN, int n4)
{
    __shared__ float sc[CH], bi[CH];
    if (threadIdx.x < CH) {
        int c = threadIdx.x;
        float mean = stats[c] * invN;
        float var  = stats[CH + c] * invN - mean * mean;
        float s = gamma[c] * rsqrtf(var + BN_EPS);
        sc[c] = s;
        bi[c] = beta[c] - mean * s;
    }
    __syncthreads();

    int tid = blockIdx.x * blockDim.x + threadIdx.x;
    int stride = gridDim.x * blockDim.x;
    for (int i = tid; i < n4; i += stride) {
        uint4 v = y4[i];
        int c = (i * 8) & (CH - 1);
        f32x4 o0, o1;
        o0[0] = fmaxf(bf2f_lo(v.x) * sc[c+0] + bi[c+0], 0.f);
        o0[1] = fmaxf(bf2f_hi(v.x) * sc[c+1] + bi[c+1], 0.f);
        o0[2] = fmaxf(bf2f_lo(v.y) * sc[c+2] + bi[c+2], 0.f);
        o0[3] = fmaxf(bf2f_hi(v.y) * sc[c+3] + bi[c+3], 0.f);
        o1[0] = fmaxf(bf2f_lo(v.z) * sc[c+4] + bi[c+4], 0.f);
        o1[1] = fmaxf(bf2f_hi(v.z) * sc[c+5] + bi[c+5], 0.f);
        o1[2] = fmaxf(bf2f_lo(v.w) * sc[c+6] + bi[c+6], 0.f);
        o1[3] = fmaxf(bf2f_hi(v.w) * sc[c+7] + bi[c+7], 0.f);
        out4[2 * i]     = o0;
        out4[2 * i + 1] = o1;
    }
}

// ---------------- f32-atomic fallback path (round-0 kernels) ----------------
__global__ __launch_bounds__(256) void conv_kernel(
    const float* __restrict__ x, const float* __restrict__ W,
    const int* __restrict__ in_idx, const int* __restrict__ out_idx,
    float* __restrict__ y, int P, int tilesPerK, int tilesPerWave)
{
    const int k    = blockIdx.y;
    const int lane = threadIdx.x & 63;
    const int wv   = threadIdx.x >> 6;
    const int r16  = lane & 15;
    const int g    = lane >> 4;

    const float* Wk = W + k * CH * CH;
    bf16x8 b0, b1;
#pragma unroll
    for (int j = 0; j < 8; ++j) {
        int kk = g * 8 + j;
        b0[j] = (short)f2bf(Wk[kk * CH + r16]);
        b1[j] = (short)f2bf(Wk[kk * CH + 16 + r16]);
    }

    const int kP = k * P;
    int t0 = (blockIdx.x * 4 + wv) * tilesPerWave;
    int t1 = t0 + tilesPerWave;
    if (t1 > tilesPerK) t1 = tilesPerK;

    for (int t = t0; t < t1; ++t) {
        const int base = t * 16;
        int pi = base + r16;
        if (pi >= P) pi = P - 1;
        const int ii = in_idx[kP + pi];
        const float* xr = x + ii * CH + g * 8;
        f32x4 x0 = *(const f32x4*)xr;
        f32x4 x1 = *(const f32x4*)(xr + 4);
        bf16x8 a;
        a[0] = (short)f2bf(x0[0]); a[1] = (short)f2bf(x0[1]);
        a[2] = (short)f2bf(x0[2]); a[3] = (short)f2bf(x0[3]);
        a[4] = (short)f2bf(x1[0]); a[5] = (short)f2bf(x1[1]);
        a[6] = (short)f2bf(x1[2]); a[7] = (short)f2bf(x1[3]);

        f32x4 d0 = {0.f, 0.f, 0.f, 0.f};
        f32x4 d1 = {0.f, 0.f, 0.f, 0.f};
        d0 = __builtin_amdgcn_mfma_f32_16x16x32_bf16(a, b0, d0, 0, 0, 0);
        d1 = __builtin_amdgcn_mfma_f32_16x16x32_bf16(a, b1, d1, 0, 0, 0);

#pragma unroll
        for (int i = 0; i < 4; ++i) {
            int pr = base + g * 4 + i;
            if (pr < P) {
                int oi = out_idx[kP + pr];
                atomicAdd(&y[oi * CH + r16], d0[i]);
                atomicAdd(&y[oi * CH + 16 + r16], d1[i]);
            }
        }
    }
}

__global__ __launch_bounds__(256) void stats_kernel(
    const f32x4* __restrict__ y4, float* __restrict__ stats, int n4)
{
    __shared__ float ls[CH], ls2[CH];
    if (threadIdx.x < CH) { ls[threadIdx.x] = 0.f; ls2[threadIdx.x] = 0.f; }
    __syncthreads();

    int tid = blockIdx.x * blockDim.x + threadIdx.x;
    int stride = gridDim.x * blockDim.x;
    float s0 = 0, s1 = 0, s2 = 0, s3 = 0;
    float q0 = 0, q1 = 0, q2 = 0, q3 = 0;
    for (int i = tid; i < n4; i += stride) {
        f32x4 v = y4[i];
        s0 += v[0]; q0 += v[0] * v[0];
        s1 += v[1]; q1 += v[1] * v[1];
        s2 += v[2]; q2 += v[2] * v[2];
        s3 += v[3]; q3 += v[3] * v[3];
    }
    int c = (tid * 4) & (CH - 1);
    atomicAdd(&ls[c + 0], s0); atomicAdd(&ls[c + 1], s1);
    atomicAdd(&ls[c + 2], s2); atomicAdd(&ls[c + 3], s3);
    atomicAdd(&ls2[c + 0], q0); atomicAdd(&ls2[c + 1], q1);
    atomicAdd(&ls2[c + 2], q2); atomicAdd(&ls2[c + 3], q3);
    __syncthreads();
    if (threadIdx.x < CH) {
        atomicAdd(&stats[threadIdx.x], ls[threadIdx.x]);
        atomicAdd(&stats[CH + threadIdx.x], ls2[threadIdx.x]);
    }
}

__global__ __launch_bounds__(256) void bn_relu_kernel(
    f32x4* __restrict__ y4, const float* __restrict__ stats,
    const float* __restrict__ gamma, const float* __restrict__ beta,
    float invN, int n4)
{
    __shared__ float sc[CH], bi[CH];
    if (threadIdx.x < CH) {
        int c = threadIdx.x;
        float mean = stats[c] * invN;
        float var  = stats[CH + c] * invN - mean * mean;
        float s = gamma[c] * rsqrtf(var + BN_EPS);
        sc[c] = s;
        bi[c] = beta[c] - mean * s;
    }
    __syncthreads();

    int tid = blockIdx.x * blockDim.x + threadIdx.x;
    int stride = gridDim.x * blockDim.x;
    for (int i = tid; i < n4; i += stride) {
        f32x4 v = y4[i];
        int c = (i * 4) & (CH - 1);
        f32x4 o;
        o[0] = fmaxf(v[0] * sc[c + 0] + bi[c + 0], 0.f);
        o[1] = fmaxf(v[1] * sc[c + 1] + bi[c + 1], 0.f);
        o[2] = fmaxf(v[2] * sc[c + 2] + bi[c + 2], 0.f);
        o[3] = fmaxf(v[3] * sc[c + 3] + bi[c + 3], 0.f);
        y4[i] = o;
    }
}

extern "C" void kernel_launch(void* const* d_in, const int* in_sizes, int n_in,
                              void* d_out, int out_size, void* d_ws, size_t ws_size,
                              hipStream_t stream)
{
    const float* x      = (const float*)d_in[0];
    const float* W      = (const float*)d_in[1];
    const float* gamma  = (const float*)d_in[2];
    const float* beta   = (const float*)d_in[3];
    const int*   in_idx = (const int*)d_in[4];
    const int*   out_idx= (const int*)d_in[5];

    const int P = in_sizes[4] / KOFF;
    const int N = in_sizes[0] / CH;

    const int tilesPerK = (P + 15) / 16;
    const int tilesPerWave = 8;
    const int blocksX = (tilesPerK + 4 * tilesPerWave - 1) / (4 * tilesPerWave);

    float* stats = (float*)d_ws;
    const size_t statsBytes = 256;                       // 64 floats, padded
    const size_t ybfBytes = (size_t)N * CH * 2;          // bf16 accumulator

    if (ws_size >= statsBytes + ybfBytes) {
        unsigned* ybf = (unsigned*)((char*)d_ws + statsBytes);
        hipMemsetAsync(d_ws, 0, statsBytes + ybfBytes, stream);

        conv_pk_kernel<<<dim3(blocksX, KOFF), 256, 0, stream>>>(
            x, W, in_idx, out_idx, ybf, P, tilesPerK, tilesPerWave);

        const int n4 = (N * CH) / 8;    // uint4 granules (8 bf16 each)
        stats_pk_kernel<<<1024, 256, 0, stream>>>((const uint4*)ybf, stats, n4);
        bn_relu_pk_kernel<<<2048, 256, 0, stream>>>(
            (const uint4*)ybf, (f32x4*)d_out, stats, gamma, beta,
            1.0f / (float)N, n4);
    } else {
        float* y = (float*)d_out;
        hipMemsetAsync(d_out, 0, (size_t)out_size * sizeof(float), stream);
        hipMemsetAsync(d_ws, 0, statsBytes, stream);

        conv_kernel<<<dim3(blocksX, KOFF), 256, 0, stream>>>(
            x, W, in_idx, out_idx, y, P, tilesPerK, tilesPerWave);

        const int n4 = out_size / 4;
        stats_kernel<<<1024, 256, 0, stream>>>((const f32x4*)d_out, stats, n4);
        bn_relu_kernel<<<2048, 256, 0, stream>>>((f32x4*)d_out, stats, gamma, beta,
                                                 1.0f / (float)N, n4);
    }
}

// Round 3
// 825.504 us; speedup vs baseline: 2.0522x; 1.0904x over previous
//
#include <hip/hip_runtime.h>

#define CH 32
#define KOFF 27
#define BN_EPS 1e-5f
#define FXS 512.0f          // fixed-point scale 2^9
#define FXI (1.0f / 512.0f)

typedef short bf16x8 __attribute__((ext_vector_type(8)));
typedef float f32x4 __attribute__((ext_vector_type(4)));
typedef unsigned long long u64;

__device__ __forceinline__ unsigned short f2bf(float f) {
    unsigned u = __builtin_bit_cast(unsigned, f);
    u = (u + 0x7fffu + ((u >> 16) & 1u)) >> 16;   // round-to-nearest-even
    return (unsigned short)u;
}

// Decode 4 sign-extended 16-bit field sums from an exact int64 accumulation.
__device__ __forceinline__ void decode4(u64 v, float* f) {
    long long w = (long long)v;
    int s0 = (short)(w & 0xFFFF);          w -= (long long)s0;
    int s1 = (short)((w >> 16) & 0xFFFF);  w -= ((long long)s1 << 16);
    int s2 = (short)((w >> 32) & 0xFFFF);  w -= ((long long)s2 << 32);
    int s3 = (int)(w >> 48);
    f[0] = s0 * FXI; f[1] = s1 * FXI; f[2] = s2 * FXI; f[3] = s3 * FXI;
}

// ---------------- fixed-point u64-atomic conv ----------------
// One wave = 16 rulebook pairs. B fragments column-permuted so lane r16 holds
// channels (2*r16, 2*r16+1). Lane pairs (r16 even/odd) exchange via shfl_xor
// to assemble 4-channel 16-bit-field addends -> one u64 atomic covers 4 ch.
// Even lanes scatter D-rows {0,1}, odd lanes rows {2,3}: 2 atomics/lane/tile.
__global__ __launch_bounds__(256) void conv_fx_kernel(
    const float* __restrict__ x, const float* __restrict__ W,
    const int* __restrict__ in_idx, const int* __restrict__ out_idx,
    u64* __restrict__ yfx,        // [N][8] u64: word m = channels 4m..4m+3
    int P, int tilesPerK, int tilesPerWave)
{
    const int k    = blockIdx.y;
    const int lane = threadIdx.x & 63;
    const int wv   = threadIdx.x >> 6;
    const int r16  = lane & 15;
    const int g    = lane >> 4;

    const float* Wk = W + k * CH * CH;
    bf16x8 b0, b1;   // b0 -> channel 2*r16, b1 -> channel 2*r16+1
#pragma unroll
    for (int j = 0; j < 8; ++j) {
        int kk = g * 8 + j;
        b0[j] = (short)f2bf(Wk[kk * CH + 2 * r16]);
        b1[j] = (short)f2bf(Wk[kk * CH + 2 * r16 + 1]);
    }

    const int kP = k * P;
    int t0 = (blockIdx.x * 4 + wv) * tilesPerWave;
    int t1 = t0 + tilesPerWave;
    if (t1 > tilesPerK) t1 = tilesPerK;

    const int iBase = (r16 & 1) ? 2 : 0;   // which D-rows this lane scatters
    const int m     = r16 >> 1;            // u64 column (channel quad)

    for (int t = t0; t < t1; ++t) {
        const int base = t * 16;
        int pi = base + r16;
        if (pi >= P) pi = P - 1;
        const int ii = in_idx[kP + pi];
        const float* xr = x + ii * CH + g * 8;
        f32x4 x0 = *(const f32x4*)xr;
        f32x4 x1 = *(const f32x4*)(xr + 4);
        bf16x8 a;
        a[0] = (short)f2bf(x0[0]); a[1] = (short)f2bf(x0[1]);
        a[2] = (short)f2bf(x0[2]); a[3] = (short)f2bf(x0[3]);
        a[4] = (short)f2bf(x1[0]); a[5] = (short)f2bf(x1[1]);
        a[6] = (short)f2bf(x1[2]); a[7] = (short)f2bf(x1[3]);

        f32x4 d0 = {0.f, 0.f, 0.f, 0.f};
        f32x4 d1 = {0.f, 0.f, 0.f, 0.f};
        d0 = __builtin_amdgcn_mfma_f32_16x16x32_bf16(a, b0, d0, 0, 0, 0);
        d1 = __builtin_amdgcn_mfma_f32_16x16x32_bf16(a, b1, d1, 0, 0, 0);

        // Quantize both channels per row, packed as 2x int16 in a u32.
        unsigned qi[4];
#pragma unroll
        for (int i = 0; i < 4; ++i) {
            int s0 = __float2int_rn(d0[i] * FXS);
            int s1 = __float2int_rn(d1[i] * FXS);
            qi[i] = (unsigned)(s0 & 0xFFFF) | ((unsigned)s1 << 16);
        }
        unsigned pq[4];
#pragma unroll
        for (int i = 0; i < 4; ++i) pq[i] = (unsigned)__shfl_xor((int)qi[i], 1);

#pragma unroll
        for (int s = 0; s < 2; ++s) {
            const int i  = iBase + s;
            const int pr = base + g * 4 + i;
            if (pr < P) {
                const int oi = out_idx[kP + pr];
                int a0 = (short)(qi[i] & 0xFFFF), a1 = (short)(qi[i] >> 16);
                int c0 = (short)(pq[i] & 0xFFFF), c1 = (short)(pq[i] >> 16);
                long long A;
                if (!(r16 & 1))   // self = ch(4m,4m+1): fields 0,1
                    A = (long long)a0 + ((long long)a1 << 16)
                      + ((long long)c0 << 32) + ((long long)c1 << 48);
                else              // self = ch(4m+2,4m+3): fields 2,3
                    A = (long long)c0 + ((long long)c1 << 16)
                      + ((long long)a0 << 32) + ((long long)a1 << 48);
                atomicAdd(&yfx[(size_t)oi * 8 + m], (u64)A);
            }
        }
    }
}

__global__ __launch_bounds__(256) void stats_fx_kernel(
    const u64* __restrict__ yfx, float* __restrict__ stats, int nW)
{
    __shared__ float ls[CH], ls2[CH];
    if (threadIdx.x < CH) { ls[threadIdx.x] = 0.f; ls2[threadIdx.x] = 0.f; }
    __syncthreads();

    int tid = blockIdx.x * blockDim.x + threadIdx.x;
    int stride = gridDim.x * blockDim.x;   // multiple of 8 -> fixed quad per thread
    float s[4] = {0,0,0,0}, q[4] = {0,0,0,0};
    for (int i = tid; i < nW; i += stride) {
        float f[4];
        decode4(yfx[i], f);
#pragma unroll
        for (int j = 0; j < 4; ++j) { s[j] += f[j]; q[j] += f[j] * f[j]; }
    }
    int c = (tid & 7) * 4;
#pragma unroll
    for (int j = 0; j < 4; ++j) {
        atomicAdd(&ls[c + j], s[j]);
        atomicAdd(&ls2[c + j], q[j]);
    }
    __syncthreads();
    if (threadIdx.x < CH) {
        atomicAdd(&stats[threadIdx.x], ls[threadIdx.x]);
        atomicAdd(&stats[CH + threadIdx.x], ls2[threadIdx.x]);
    }
}

__global__ __launch_bounds__(256) void bn_relu_fx_kernel(
    const u64* __restrict__ yfx, f32x4* __restrict__ out4,
    const float* __restrict__ stats,
    const float* __restrict__ gamma, const float* __restrict__ beta,
    float invN, int nW)
{
    __shared__ float sc[CH], bi[CH];
    if (threadIdx.x < CH) {
        int c = threadIdx.x;
        float mean = stats[c] * invN;
        float var  = stats[CH + c] * invN - mean * mean;
        float s = gamma[c] * rsqrtf(var + BN_EPS);
        sc[c] = s;
        bi[c] = beta[c] - mean * s;
    }
    __syncthreads();

    int tid = blockIdx.x * blockDim.x + threadIdx.x;
    int stride = gridDim.x * blockDim.x;
    for (int i = tid; i < nW; i += stride) {
        float f[4];
        decode4(yfx[i], f);
        int c = (i & 7) * 4;
        f32x4 o;
        o[0] = fmaxf(f[0] * sc[c + 0] + bi[c + 0], 0.f);
        o[1] = fmaxf(f[1] * sc[c + 1] + bi[c + 1], 0.f);
        o[2] = fmaxf(f[2] * sc[c + 2] + bi[c + 2], 0.f);
        o[3] = fmaxf(f[3] * sc[c + 3] + bi[c + 3], 0.f);
        out4[i] = o;
    }
}

// ---------------- f32-atomic fallback (ws too small) ----------------
__global__ __launch_bounds__(256) void conv_kernel(
    const float* __restrict__ x, const float* __restrict__ W,
    const int* __restrict__ in_idx, const int* __restrict__ out_idx,
    float* __restrict__ y, int P, int tilesPerK, int tilesPerWave)
{
    const int k    = blockIdx.y;
    const int lane = threadIdx.x & 63;
    const int wv   = threadIdx.x >> 6;
    const int r16  = lane & 15;
    const int g    = lane >> 4;

    const float* Wk = W + k * CH * CH;
    bf16x8 b0, b1;
#pragma unroll
    for (int j = 0; j < 8; ++j) {
        int kk = g * 8 + j;
        b0[j] = (short)f2bf(Wk[kk * CH + r16]);
        b1[j] = (short)f2bf(Wk[kk * CH + 16 + r16]);
    }

    const int kP = k * P;
    int t0 = (blockIdx.x * 4 + wv) * tilesPerWave;
    int t1 = t0 + tilesPerWave;
    if (t1 > tilesPerK) t1 = tilesPerK;

    for (int t = t0; t < t1; ++t) {
        const int base = t * 16;
        int pi = base + r16;
        if (pi >= P) pi = P - 1;
        const int ii = in_idx[kP + pi];
        const float* xr = x + ii * CH + g * 8;
        f32x4 x0 = *(const f32x4*)xr;
        f32x4 x1 = *(const f32x4*)(xr + 4);
        bf16x8 a;
        a[0] = (short)f2bf(x0[0]); a[1] = (short)f2bf(x0[1]);
        a[2] = (short)f2bf(x0[2]); a[3] = (short)f2bf(x0[3]);
        a[4] = (short)f2bf(x1[0]); a[5] = (short)f2bf(x1[1]);
        a[6] = (short)f2bf(x1[2]); a[7] = (short)f2bf(x1[3]);

        f32x4 d0 = {0.f, 0.f, 0.f, 0.f};
        f32x4 d1 = {0.f, 0.f, 0.f, 0.f};
        d0 = __builtin_amdgcn_mfma_f32_16x16x32_bf16(a, b0, d0, 0, 0, 0);
        d1 = __builtin_amdgcn_mfma_f32_16x16x32_bf16(a, b1, d1, 0, 0, 0);

#pragma unroll
        for (int i = 0; i < 4; ++i) {
            int pr = base + g * 4 + i;
            if (pr < P) {
                int oi = out_idx[kP + pr];
                atomicAdd(&y[oi * CH + r16], d0[i]);
                atomicAdd(&y[oi * CH + 16 + r16], d1[i]);
            }
        }
    }
}

__global__ __launch_bounds__(256) void stats_kernel(
    const f32x4* __restrict__ y4, float* __restrict__ stats, int n4)
{
    __shared__ float ls[CH], ls2[CH];
    if (threadIdx.x < CH) { ls[threadIdx.x] = 0.f; ls2[threadIdx.x] = 0.f; }
    __syncthreads();

    int tid = blockIdx.x * blockDim.x + threadIdx.x;
    int stride = gridDim.x * blockDim.x;
    float s0 = 0, s1 = 0, s2 = 0, s3 = 0;
    float q0 = 0, q1 = 0, q2 = 0, q3 = 0;
    for (int i = tid; i < n4; i += stride) {
        f32x4 v = y4[i];
        s0 += v[0]; q0 += v[0] * v[0];
        s1 += v[1]; q1 += v[1] * v[1];
        s2 += v[2]; q2 += v[2] * v[2];
        s3 += v[3]; q3 += v[3] * v[3];
    }
    int c = (tid * 4) & (CH - 1);
    atomicAdd(&ls[c + 0], s0); atomicAdd(&ls[c + 1], s1);
    atomicAdd(&ls[c + 2], s2); atomicAdd(&ls[c + 3], s3);
    atomicAdd(&ls2[c + 0], q0); atomicAdd(&ls2[c + 1], q1);
    atomicAdd(&ls2[c + 2], q2); atomicAdd(&ls2[c + 3], q3);
    __syncthreads();
    if (threadIdx.x < CH) {
        atomicAdd(&stats[threadIdx.x], ls[threadIdx.x]);
        atomicAdd(&stats[CH + threadIdx.x], ls2[threadIdx.x]);
    }
}

__global__ __launch_bounds__(256) void bn_relu_kernel(
    f32x4* __restrict__ y4, const float* __restrict__ stats,
    const float* __restrict__ gamma, const float* __restrict__ beta,
    float invN, int n4)
{
    __shared__ float sc[CH], bi[CH];
    if (threadIdx.x < CH) {
        int c = threadIdx.x;
        float mean = stats[c] * invN;
        float var  = stats[CH + c] * invN - mean * mean;
        float s = gamma[c] * rsqrtf(var + BN_EPS);
        sc[c] = s;
        bi[c] = beta[c] - mean * s;
    }
    __syncthreads();

    int tid = blockIdx.x * blockDim.x + threadIdx.x;
    int stride = gridDim.x * blockDim.x;
    for (int i = tid; i < n4; i += stride) {
        f32x4 v = y4[i];
        int c = (i * 4) & (CH - 1);
        f32x4 o;
        o[0] = fmaxf(v[0] * sc[c + 0] + bi[c + 0], 0.f);
        o[1] = fmaxf(v[1] * sc[c + 1] + bi[c + 1], 0.f);
        o[2] = fmaxf(v[2] * sc[c + 2] + bi[c + 2], 0.f);
        o[3] = fmaxf(v[3] * sc[c + 3] + bi[c + 3], 0.f);
        y4[i] = o;
    }
}

extern "C" void kernel_launch(void* const* d_in, const int* in_sizes, int n_in,
                              void* d_out, int out_size, void* d_ws, size_t ws_size,
                              hipStream_t stream)
{
    const float* x      = (const float*)d_in[0];
    const float* W      = (const float*)d_in[1];
    const float* gamma  = (const float*)d_in[2];
    const float* beta   = (const float*)d_in[3];
    const int*   in_idx = (const int*)d_in[4];
    const int*   out_idx= (const int*)d_in[5];

    const int P = in_sizes[4] / KOFF;
    const int N = in_sizes[0] / CH;

    const int tilesPerK = (P + 15) / 16;
    const int tilesPerWave = 8;
    const int blocksX = (tilesPerK + 4 * tilesPerWave - 1) / (4 * tilesPerWave);

    float* stats = (float*)d_ws;
    const size_t statsBytes = 256;
    const size_t yfxBytes = (size_t)N * 8 * sizeof(u64);   // 64 MB

    if (ws_size >= statsBytes + yfxBytes) {
        u64* yfx = (u64*)((char*)d_ws + statsBytes);
        hipMemsetAsync(d_ws, 0, statsBytes + yfxBytes, stream);

        conv_fx_kernel<<<dim3(blocksX, KOFF), 256, 0, stream>>>(
            x, W, in_idx, out_idx, yfx, P, tilesPerK, tilesPerWave);

        const int nW = N * 8;
        stats_fx_kernel<<<1024, 256, 0, stream>>>(yfx, stats, nW);
        bn_relu_fx_kernel<<<2048, 256, 0, stream>>>(yfx, (f32x4*)d_out, stats,
                                                    gamma, beta, 1.0f / (float)N, nW);
    } else {
        float* y = (float*)d_out;
        hipMemsetAsync(d_out, 0, (size_t)out_size * sizeof(float), stream);
        hipMemsetAsync(d_ws, 0, statsBytes, stream);

        conv_kernel<<<dim3(blocksX, KOFF), 256, 0, stream>>>(
            x, W, in_idx, out_idx, y, P, tilesPerK, tilesPerWave);

        const int n4 = out_size / 4;
        stats_kernel<<<1024, 256, 0, stream>>>((const f32x4*)d_out, stats, n4);
        bn_relu_kernel<<<2048, 256, 0, stream>>>((f32x4*)d_out, stats, gamma, beta,
                                                 1.0f / (float)N, n4);
    }
}